// Round 8
// baseline (282.335 us; speedup 1.0000x reference)
//
#include <hip/hip_runtime.h>
#include <hip/hip_bf16.h>
#include <math.h>

#define NEG_SLOPE 0.2f
#define GAT_EPS 1e-16f

constexpr int NN = 50000;   // nodes
constexpr int NE = 800000;  // raw edges
constexpr int EP = NE + NN; // edges incl. self loops = 850000
constexpr int NB = (NN + 255) / 256; // scan blocks = 196

// CSR-build geometry
constexpr int PB  = 128;                  // histogram blocks
constexpr int PT  = 1024;                 // threads per histogram block
constexpr int CH  = (EP + PB - 1) / PB;   // edges per block = 6641
constexpr int NCH = 4;                    // block-row chunks
constexpr int BPC = PB / NCH;             // 32 block-rows per chunk

__device__ inline void edge_sd(const int* __restrict__ ei, int i, int& s, int& d) {
    if (i < NE) { s = ei[i]; d = ei[NE + i]; }
    else        { s = d = i - NE; }
}

__device__ inline float bflo(unsigned int h) { return __uint_as_float(h << 16); }
__device__ inline float bfhi(unsigned int h) { return __uint_as_float(h & 0xffff0000u); }

// ---------------- CSR build, zero device-scope atomics ----------------
__global__ __launch_bounds__(PT) void k_p1_hist(const int* __restrict__ ei,
                                                float* __restrict__ out0,
                                                unsigned char* __restrict__ hist,
                                                unsigned char* __restrict__ rank8) {
    __shared__ unsigned int sh[NN / 4]; // 12500 words = 50KB
    int b = blockIdx.x, t = threadIdx.x;
    for (int w = t; w < NN / 4; w += PT) sh[w] = 0u;
    __syncthreads();
    int i0 = b * CH;
    int iend = i0 + CH; if (iend > EP) iend = EP;
    for (int i = i0 + t; i < iend; i += PT) {
        int s, d; edge_sd(ei, i, s, d);
        __builtin_nontemporal_store((float)s, &out0[i]);
        __builtin_nontemporal_store((float)d, &out0[EP + i]);
        int sft = (d & 3) * 8;
        unsigned int old = atomicAdd(&sh[d >> 2], 1u << sft); // LDS atomic, CU-local
        __builtin_nontemporal_store((unsigned char)(old >> sft), &rank8[i]);
    }
    __syncthreads();
    unsigned int* hw = (unsigned int*)(hist + (size_t)b * NN);
    for (int w = t; w < NN / 4; w += PT) hw[w] = sh[w];
}

// Fused p2+scan1: register-pipelined column scan of all PB hist rows per node,
// packed chunkoff, then block scan of per-node totals -> partial rowptr + bsum.
__global__ __launch_bounds__(256) void k_p2s1(unsigned char* __restrict__ hist,
                                              unsigned char* __restrict__ chunkoff,
                                              int* __restrict__ rowptr,
                                              int* __restrict__ bsum) {
    __shared__ int sh[256];
    int t = threadIdx.x;
    int n = blockIdx.x * 256 + t;
    int v = 0;
    if (n < NN) {
        unsigned int runs[NCH];
#pragma unroll
        for (int c = 0; c < NCH; ++c) {
            size_t base = (size_t)(c * BPC) * NN + n;
            unsigned int vv[BPC];
#pragma unroll
            for (int b = 0; b < BPC; ++b) vv[b] = hist[base + (size_t)b * NN];
            unsigned int run = 0;
#pragma unroll
            for (int b = 0; b < BPC; ++b) { unsigned int x = vv[b]; vv[b] = run; run += x; }
#pragma unroll
            for (int b = 0; b < BPC; ++b) hist[base + (size_t)b * NN] = (unsigned char)vv[b];
            runs[c] = run;
        }
        unsigned int o1 = runs[0], o2 = o1 + runs[1], o3 = o2 + runs[2];
        *(unsigned int*)&chunkoff[(size_t)n * 4] = (o1 << 8) | (o2 << 16) | (o3 << 24);
        v = (int)(o3 + runs[3]);
    }
    sh[t] = v; __syncthreads();
    for (int off = 1; off < 256; off <<= 1) {
        int x = (t >= off) ? sh[t - off] : 0;
        __syncthreads();
        sh[t] += x;
        __syncthreads();
    }
    if (n < NN) rowptr[n] = sh[t] - v;
    if (t == 255) bsum[blockIdx.x] = sh[255];
}

// CSR fill + folded scan2/scan3: every block scans bsum (196 ints) in LDS,
// uses the exclusive offsets for pos, and writes the finalized rowptrF.
__global__ __launch_bounds__(256) void k_fill(const int* __restrict__ ei,
                                              const unsigned char* __restrict__ rank8,
                                              const unsigned char* __restrict__ hist,
                                              const unsigned char* __restrict__ chunkoff,
                                              const int* __restrict__ rowptr,
                                              const int* __restrict__ bsum,
                                              unsigned short* __restrict__ col,
                                              int* __restrict__ rowptrF) {
    __shared__ int sb[256];
    int t = threadIdx.x;
    int v = (t < NB) ? bsum[t] : 0;
    sb[t] = v; __syncthreads();
    for (int off = 1; off < 256; off <<= 1) {
        int x = (t >= off) ? sb[t - off] : 0;
        __syncthreads();
        sb[t] += x;
        __syncthreads();
    }
    sb[t] -= v;              // exclusive scan
    __syncthreads();
    int i = blockIdx.x * 256 + t;
    if (i < EP) {
        int b = i / CH;      // hist block-row (const divide -> magic mul)
        int c = b / BPC;     // chunk
        int s, d; edge_sd(ei, i, s, d);
        int pos = rowptr[d] + sb[d >> 8] + (int)chunkoff[d * 4 + c]
                + (int)hist[(size_t)b * NN + d] + (int)rank8[i];
        col[pos] = (unsigned short)s;
    }
    if (i < NN) rowptrF[i] = rowptr[i] + sb[i >> 8];
    if (i == 0) rowptrF[NN] = EP;
}

// edge-order alpha output (coalesced NT write; score arrays L2-resident)
__global__ void k_alpha_out(const int* __restrict__ ei, const float* __restrict__ as_,
                            const float* __restrict__ ad_, const float* __restrict__ inv,
                            float* __restrict__ out_alpha) {
    int i = blockIdx.x * blockDim.x + threadIdx.x;
    if (i >= EP) return;
    int s, d; edge_sd(ei, i, s, d);
    float v = as_[s] + ad_[d];
    v = v > 0.f ? v : NEG_SLOPE * v;
    __builtin_nontemporal_store(__expf(v) * inv[d], &out_alpha[i]);
}

// ---------------- dense GEMM + fused alpha scores (layer 1) ----------------
struct alignas(8) bh4 { __hip_bfloat16 a, b, c, d; };
struct alignas(4) bh2 { __hip_bfloat16 a, b; };

__device__ inline void fma4(float4& acc, float x, const float4& w) {
    acc.x = fmaf(x, w.x, acc.x);
    acc.y = fmaf(x, w.y, acc.y);
    acc.z = fmaf(x, w.z, acc.z);
    acc.w = fmaf(x, w.w, acc.w);
}

template <int FIN, int FOUT, int NPB>
__global__ __launch_bounds__(256) void k_gemm_t(const float* __restrict__ in,
                                                const float* __restrict__ W,
                                                const float* __restrict__ avs,
                                                const float* __restrict__ avd,
                                                __hip_bfloat16* __restrict__ H,
                                                float* __restrict__ as_,
                                                float* __restrict__ ad_, int n) {
    constexpr int TF = FOUT / 4;
    constexpr int XS = FIN + 4;
    constexpr int WS = FOUT + 4;
    __shared__ float sX[NPB * XS];
    __shared__ float sWt[FIN * WS];
    int tid = threadIdx.x;
    for (int idx = tid; idx < FIN * FOUT; idx += 256) {
        int f = idx % FOUT, k = idx / FOUT;
        sWt[k * WS + f] = W[f * FIN + k];
    }
    int nb = blockIdx.x * NPB;
    for (int idx = tid; idx < NPB * (FIN / 4); idx += 256) {
        int node = idx / (FIN / 4), kq = idx % (FIN / 4);
        int g = nb + node;
        float4 v = make_float4(0.f, 0.f, 0.f, 0.f);
        if (g < n) v = *(const float4*)&in[(size_t)g * FIN + kq * 4];
        *(float4*)&sX[node * XS + kq * 4] = v;
    }
    __syncthreads();

    int fq = tid % TF, ng = tid / TF;
    int n0 = ng * 4;
    float4 acc0 = make_float4(0.f, 0.f, 0.f, 0.f);
    float4 acc1 = acc0, acc2 = acc0, acc3 = acc0;
    for (int k = 0; k < FIN; k += 4) {
        float4 w0 = *(const float4*)&sWt[(k + 0) * WS + fq * 4];
        float4 w1 = *(const float4*)&sWt[(k + 1) * WS + fq * 4];
        float4 w2 = *(const float4*)&sWt[(k + 2) * WS + fq * 4];
        float4 w3 = *(const float4*)&sWt[(k + 3) * WS + fq * 4];
        float4 x0 = *(const float4*)&sX[(n0 + 0) * XS + k];
        float4 x1 = *(const float4*)&sX[(n0 + 1) * XS + k];
        float4 x2 = *(const float4*)&sX[(n0 + 2) * XS + k];
        float4 x3 = *(const float4*)&sX[(n0 + 3) * XS + k];
        fma4(acc0, x0.x, w0); fma4(acc0, x0.y, w1); fma4(acc0, x0.z, w2); fma4(acc0, x0.w, w3);
        fma4(acc1, x1.x, w0); fma4(acc1, x1.y, w1); fma4(acc1, x1.z, w2); fma4(acc1, x1.w, w3);
        fma4(acc2, x2.x, w0); fma4(acc2, x2.y, w1); fma4(acc2, x2.z, w2); fma4(acc2, x2.w, w3);
        fma4(acc3, x3.x, w0); fma4(acc3, x3.y, w1); fma4(acc3, x3.z, w2); fma4(acc3, x3.w, w3);
    }
    float4 accs[4] = {acc0, acc1, acc2, acc3};
    float4 vs4 = *(const float4*)&avs[fq * 4];
    float4 vd4 = *(const float4*)&avd[fq * 4];
#pragma unroll
    for (int j = 0; j < 4; ++j) {
        int g = nb + n0 + j;
        float ps = accs[j].x * vs4.x + accs[j].y * vs4.y + accs[j].z * vs4.z + accs[j].w * vs4.w;
        float pd = accs[j].x * vd4.x + accs[j].y * vd4.y + accs[j].z * vd4.z + accs[j].w * vd4.w;
#pragma unroll
        for (int off = TF / 2; off; off >>= 1) {
            ps += __shfl_down(ps, off, TF);
            pd += __shfl_down(pd, off, TF);
        }
        if (g < n) {
            if (fq == 0) { as_[g] = ps; ad_[g] = pd; }
            bh4 o;
            o.a = __float2bfloat16(accs[j].x);
            o.b = __float2bfloat16(accs[j].y);
            o.c = __float2bfloat16(accs[j].z);
            o.d = __float2bfloat16(accs[j].w);
            *(bh4*)&H[(size_t)g * FOUT + fq * 4] = o;
        }
    }
}

// ------- FUSED: group-per-node attn (64-in) + block-level next-layer GEMM -------
// Attn phase = k_attn_grp<64> writing h rows into LDS (not global). Barrier.
// GEMM phase: 16 threads/node x 4 (or 2) feats, W staged once in LDS
// (broadcast + 2-way bank reads = free). Next-layer scores reduced per node.
// Replaces standalone mid-layer GEMM; kills the 25.6MB agg round-trip.
// NPB=16 nodes/block; NN = 3125*16 exactly -> no tail.
template <int GOUT, bool WRITE_INV>
__global__ __launch_bounds__(256) void k_attn_fg(
    const int* __restrict__ rowptr, const unsigned short* __restrict__ col,
    const float* __restrict__ as_, const float* __restrict__ ad_,
    const __hip_bfloat16* __restrict__ H, const float* __restrict__ bias,
    const float* __restrict__ Wn,   // [GOUT][64]
    const float* __restrict__ avs, const float* __restrict__ avd, // [GOUT]
    __hip_bfloat16* __restrict__ Hout,  // [NN][GOUT]
    float* __restrict__ as_out, float* __restrict__ ad_out,
    float* __restrict__ inv_out) {
    constexpr int NPB = 16;
    __shared__ float sW[64][GOUT + 2];
    __shared__ float sA[NPB][68];
    int tid = threadIdx.x;
    for (int idx = tid; idx < 64 * GOUT; idx += 256) {
        int f = idx % GOUT, k = idx / GOUT;
        sW[k][f] = Wn[f * 64 + k];
    }

    // ---- attn phase (L=16 lanes per node, 4 nodes per wave) ----
    int lane = tid & 63;
    int grp = lane >> 4, gl = lane & 15;
    int lnode = (tid >> 6) * 4 + grp;            // 0..15
    int node = blockIdx.x * NPB + lnode;
    int base = lane & ~15;

    if (node < NN) {
        int start = rowptr[node], end = rowptr[node + 1];
        float adv = ad_[node];
        const uint2* __restrict__ H4 = (const uint2*)H;
        float sloc = 0.f;
        float4 acc = make_float4(0.f, 0.f, 0.f, 0.f);
        for (int c = start; c < end; c += 8) {
            int e = c + gl;
            float p = 0.f;
            int sc = 0;
            if (gl < 8 && e < end) {
                sc = (int)col[e];
                float v = as_[sc] + adv;
                v = v > 0.f ? v : NEG_SLOPE * v;
                p = __expf(v);
            }
            sloc += p;
            int cnt = end - c; if (cnt > 8) cnt = 8;
            float pp[8]; int ss[8]; uint2 hh[8];
#pragma unroll
            for (int k = 0; k < 8; ++k) {
                pp[k] = __shfl(p, base + k);
                ss[k] = __shfl(sc, base + k);
            }
#pragma unroll
            for (int k = 0; k < 8; ++k) {
                hh[k] = make_uint2(0u, 0u);
                if (k < cnt) hh[k] = H4[(size_t)ss[k] * 16 + gl];
            }
#pragma unroll
            for (int k = 0; k < 8; ++k) {
                acc.x = fmaf(pp[k], bflo(hh[k].x), acc.x);
                acc.y = fmaf(pp[k], bfhi(hh[k].x), acc.y);
                acc.z = fmaf(pp[k], bflo(hh[k].y), acc.z);
                acc.w = fmaf(pp[k], bfhi(hh[k].y), acc.w);
            }
        }
#pragma unroll
        for (int off = 8; off; off >>= 1) sloc += __shfl_xor(sloc, off);
        float inv = 1.f / (sloc + GAT_EPS);
        if (WRITE_INV && gl == 0) inv_out[node] = inv;

        float4 bb = *(const float4*)&bias[gl * 4];
        sA[lnode][gl * 4 + 0] = fmaxf(bb.x + acc.x * inv, 0.f);
        sA[lnode][gl * 4 + 1] = fmaxf(bb.y + acc.y * inv, 0.f);
        sA[lnode][gl * 4 + 2] = fmaxf(bb.z + acc.z * inv, 0.f);
        sA[lnode][gl * 4 + 3] = fmaxf(bb.w + acc.w * inv, 0.f);
    }
    __syncthreads();

    // ---- GEMM phase: thread t -> node tid>>4, feature slot tid&15 ----
    int ng = tid >> 4, fq = tid & 15;
    int gnode = blockIdx.x * NPB + ng;
    if (gnode >= NN) return;
    if (GOUT == 64) {
        float4 a = make_float4(0.f, 0.f, 0.f, 0.f);
#pragma unroll 8
        for (int k = 0; k < 64; ++k) {
            float xk = sA[ng][k];                 // broadcast within node group
            const float* wr = &sW[k][fq * 4];
            a.x = fmaf(xk, wr[0], a.x);
            a.y = fmaf(xk, wr[1], a.y);
            a.z = fmaf(xk, wr[2], a.z);
            a.w = fmaf(xk, wr[3], a.w);
        }
        float4 vs = *(const float4*)&avs[fq * 4];
        float4 vd = *(const float4*)&avd[fq * 4];
        float ps = a.x * vs.x + a.y * vs.y + a.z * vs.z + a.w * vs.w;
        float pd = a.x * vd.x + a.y * vd.y + a.z * vd.z + a.w * vd.w;
#pragma unroll
        for (int off = 8; off; off >>= 1) {
            ps += __shfl_xor(ps, off);
            pd += __shfl_xor(pd, off);
        }
        if (fq == 0) { as_out[gnode] = ps; ad_out[gnode] = pd; }
        bh4 o;
        o.a = __float2bfloat16(a.x);
        o.b = __float2bfloat16(a.y);
        o.c = __float2bfloat16(a.z);
        o.d = __float2bfloat16(a.w);
        *(bh4*)&Hout[(size_t)gnode * 64 + fq * 4] = o;
    } else { // GOUT == 32: 2 feats/thread
        float ax = 0.f, ay = 0.f;
#pragma unroll 8
        for (int k = 0; k < 64; ++k) {
            float xk = sA[ng][k];
            const float* wr = &sW[k][fq * 2];
            ax = fmaf(xk, wr[0], ax);
            ay = fmaf(xk, wr[1], ay);
        }
        float ps = ax * avs[fq * 2] + ay * avs[fq * 2 + 1];
        float pd = ax * avd[fq * 2] + ay * avd[fq * 2 + 1];
#pragma unroll
        for (int off = 8; off; off >>= 1) {
            ps += __shfl_xor(ps, off);
            pd += __shfl_xor(pd, off);
        }
        if (fq == 0) { as_out[gnode] = ps; ad_out[gnode] = pd; }
        bh2 o;
        o.a = __float2bfloat16(ax);
        o.b = __float2bfloat16(ay);
        *(bh2*)&Hout[(size_t)gnode * 32 + fq * 2] = o;
    }
}

// ---------------- plain group-per-node attn (final layer) ----------------
template <int FOUT, bool RELU, bool WRITE_INV>
__global__ __launch_bounds__(256) void k_attn_grp(
    const int* __restrict__ rowptr, const unsigned short* __restrict__ col,
    const float* __restrict__ as_, const float* __restrict__ ad_,
    const __hip_bfloat16* __restrict__ H, const float* __restrict__ bias,
    float* __restrict__ outp, float* __restrict__ inv_out) {
    constexpr int L = (FOUT == 64) ? 16 : 8;
    constexpr int GPW = 64 / L;
    int tid = blockIdx.x * 256 + threadIdx.x;
    int wid = tid >> 6;
    int lane = threadIdx.x & 63;
    int grp = lane / L;
    int gl  = lane & (L - 1);
    int node = wid * GPW + grp;
    if (node >= NN) return;

    int start = rowptr[node], end = rowptr[node + 1];
    float adv = ad_[node];
    const uint2* __restrict__ H4 = (const uint2*)H;
    int base = lane & ~(L - 1);

    float sloc = 0.f;
    float4 acc = make_float4(0.f, 0.f, 0.f, 0.f);
    for (int c = start; c < end; c += 8) {
        int e = c + gl;
        float p = 0.f;
        int sc = 0;
        if (gl < 8 && e < end) {
            sc = (int)col[e];
            float v = as_[sc] + adv;
            v = v > 0.f ? v : NEG_SLOPE * v;
            p = __expf(v);
        }
        sloc += p;
        int cnt = end - c; if (cnt > 8) cnt = 8;
        float pp[8]; int ss[8]; uint2 hh[8];
#pragma unroll
        for (int k = 0; k < 8; ++k) {
            pp[k] = __shfl(p, base + k);
            ss[k] = __shfl(sc, base + k);
        }
#pragma unroll
        for (int k = 0; k < 8; ++k) {
            hh[k] = make_uint2(0u, 0u);
            if (k < cnt) hh[k] = H4[(size_t)ss[k] * L + gl];
        }
#pragma unroll
        for (int k = 0; k < 8; ++k) {
            acc.x = fmaf(pp[k], bflo(hh[k].x), acc.x);
            acc.y = fmaf(pp[k], bfhi(hh[k].x), acc.y);
            acc.z = fmaf(pp[k], bflo(hh[k].y), acc.z);
            acc.w = fmaf(pp[k], bfhi(hh[k].y), acc.w);
        }
    }
#pragma unroll
    for (int off = L / 2; off; off >>= 1) sloc += __shfl_xor(sloc, off);
    float inv = 1.f / (sloc + GAT_EPS);
    if (WRITE_INV && gl == 0) inv_out[node] = inv;

    float4 bb = *(const float4*)&bias[gl * 4];
    float o0 = bb.x + acc.x * inv;
    float o1 = bb.y + acc.y * inv;
    float o2 = bb.z + acc.z * inv;
    float o3 = bb.w + acc.w * inv;
    if (RELU) {
        o0 = fmaxf(o0, 0.f); o1 = fmaxf(o1, 0.f);
        o2 = fmaxf(o2, 0.f); o3 = fmaxf(o3, 0.f);
    }
    *(float4*)&outp[(size_t)node * FOUT + gl * 4] = make_float4(o0, o1, o2, o3);
}

extern "C" void kernel_launch(void* const* d_in, const int* in_sizes, int n_in,
                              void* d_out, int out_size, void* d_ws, size_t ws_size,
                              hipStream_t stream) {
    const float* x  = (const float*)d_in[0];
    const int*   ei = (const int*)d_in[1];
    const float* W1 = (const float*)d_in[2];
    const float* as1 = (const float*)d_in[3];
    const float* ad1 = (const float*)d_in[4];
    const float* b1 = (const float*)d_in[5];
    const float* W2 = (const float*)d_in[6];
    const float* as2 = (const float*)d_in[7];
    const float* ad2 = (const float*)d_in[8];
    const float* b2 = (const float*)d_in[9];
    const float* W3 = (const float*)d_in[10];
    const float* as3 = (const float*)d_in[11];
    const float* ad3 = (const float*)d_in[12];
    const float* b3 = (const float*)d_in[13];

    float* out = (float*)d_out;
    float* out_edges = out;                 // [2, EP]
    float* out_alpha = out + 2 * EP;        // [EP]
    float* out_final = out + 3 * EP;        // [N, 32] = 6.4MB, written only by attn3

    char* w = (char*)d_ws;
    size_t o = 0;
    auto alloc = [&](size_t bytes) { void* p = w + o; o = (o + bytes + 15) & ~15ull; return p; };
    float* asA = (float*)alloc((size_t)NN * 4);
    float* adA = (float*)alloc((size_t)NN * 4);
    float* asB = (float*)alloc((size_t)NN * 4);
    float* adB = (float*)alloc((size_t)NN * 4);
    float* asC = (float*)alloc((size_t)NN * 4);
    float* adC = (float*)alloc((size_t)NN * 4);
    float* inv = (float*)alloc((size_t)NN * 4);
    __hip_bfloat16* H1 = (__hip_bfloat16*)alloc((size_t)NN * 64 * 2); // 6.4MB
    __hip_bfloat16* H2 = (__hip_bfloat16*)alloc((size_t)NN * 64 * 2); // 6.4MB
    __hip_bfloat16* H3 = (__hip_bfloat16*)alloc((size_t)NN * 32 * 2); // 3.2MB
    int* rowptr  = (int*)alloc((size_t)(NN + 1) * 4);
    int* rowptrF = (int*)alloc((size_t)(NN + 1) * 4);
    unsigned char* rank8 = (unsigned char*)alloc((size_t)EP);        // 0.85MB
    unsigned short* col  = (unsigned short*)alloc((size_t)EP * 2);   // 1.7MB
    unsigned char* chunkoff = (unsigned char*)alloc((size_t)NN * 4); // 200KB
    int* bsum = (int*)alloc(1024);

    const size_t histBytes = (size_t)PB * NN;           // 6.4MB
    unsigned char* hist = (ws_size >= o + histBytes)
        ? (unsigned char*)(w + o)
        : (unsigned char*)out_final; // dead until the final attn dispatch

    // --- CSR build: 3 launches (s23 folded into fill) ---
    k_p1_hist<<<PB, PT, 0, stream>>>(ei, out_edges, hist, rank8);
    k_p2s1<<<NB, 256, 0, stream>>>(hist, chunkoff, rowptr, bsum);
    k_fill<<<(EP + 255) / 256, 256, 0, stream>>>(ei, rank8, hist, chunkoff, rowptr, bsum,
                                                 col, rowptrF);

    const int nblkF  = NN / 16;          // 3125 (exact)
    const int nblk32 = (NN + 31) / 32;   // final attn: 8-lane groups

    // layer 1 GEMM: x @ W1 -> H1 (bf16) + layer-1 scores
    k_gemm_t<128, 64, 64><<<(NN + 63) / 64, 256, 0, stream>>>(x, W1, as1, ad1, H1,
                                                              asA, adA, NN);
    // attn1 + fused gemm2 -> H2, layer-2 scores, inv
    k_attn_fg<64, true><<<nblkF, 256, 0, stream>>>(rowptrF, col, asA, adA, H1, b1,
                                                   W2, as2, ad2, H2, asB, adB, inv);
    // alpha output (layer-1 scores + inv)
    k_alpha_out<<<(EP + 255) / 256, 256, 0, stream>>>(ei, asA, adA, inv, out_alpha);

    // attn2 + fused gemm3 -> H3, layer-3 scores
    k_attn_fg<32, false><<<nblkF, 256, 0, stream>>>(rowptrF, col, asB, adB, H2, b2,
                                                    W3, as3, ad3, H3, asC, adC, nullptr);
    // attn3: final aggregate + bias -> out_final
    k_attn_grp<32, false, false><<<nblk32, 256, 0, stream>>>(rowptrF, col, asC, adC, H3, b3,
                                                             out_final, nullptr);
}

// Round 9
// 275.938 us; speedup vs baseline: 1.0232x; 1.0232x over previous
//
#include <hip/hip_runtime.h>
#include <hip/hip_bf16.h>
#include <math.h>

#define NEG_SLOPE 0.2f
#define GAT_EPS 1e-16f

constexpr int NN = 50000;   // nodes
constexpr int NE = 800000;  // raw edges
constexpr int EP = NE + NN; // edges incl. self loops = 850000
constexpr int NB = (NN + 255) / 256; // scan blocks = 196

// CSR-build geometry: 256 blocks -> one 50KB-LDS block per CU (was 128 = half idle)
constexpr int PB  = 256;                  // histogram blocks
constexpr int PT  = 1024;                 // threads per histogram block
constexpr int CH  = (EP + PB - 1) / PB;   // edges per block = 3321
constexpr int NCH = 8;                    // block-row chunks
constexpr int BPC = PB / NCH;             // 32 block-rows per chunk

__device__ inline void edge_sd(const int* __restrict__ ei, int i, int& s, int& d) {
    if (i < NE) { s = ei[i]; d = ei[NE + i]; }
    else        { s = d = i - NE; }
}

__device__ inline float bflo(unsigned int h) { return __uint_as_float(h << 16); }
__device__ inline float bfhi(unsigned int h) { return __uint_as_float(h & 0xffff0000u); }

// ---------------- CSR build, zero device-scope atomics ----------------
__global__ __launch_bounds__(PT) void k_p1_hist(const int* __restrict__ ei,
                                                float* __restrict__ out0,
                                                unsigned char* __restrict__ hist,
                                                unsigned char* __restrict__ rank8) {
    __shared__ unsigned int sh[NN / 4]; // 12500 words = 50KB
    int b = blockIdx.x, t = threadIdx.x;
    for (int w = t; w < NN / 4; w += PT) sh[w] = 0u;
    __syncthreads();
    int i0 = b * CH;
    int iend = i0 + CH; if (iend > EP) iend = EP;
    for (int i = i0 + t; i < iend; i += PT) {
        int s, d; edge_sd(ei, i, s, d);
        __builtin_nontemporal_store((float)s, &out0[i]);
        __builtin_nontemporal_store((float)d, &out0[EP + i]);
        int sft = (d & 3) * 8;
        unsigned int old = atomicAdd(&sh[d >> 2], 1u << sft); // LDS atomic, CU-local
        __builtin_nontemporal_store((unsigned char)(old >> sft), &rank8[i]);
    }
    __syncthreads();
    unsigned int* hw = (unsigned int*)(hist + (size_t)b * NN);
    for (int w = t; w < NN / 4; w += PT) hw[w] = sh[w];
}

// Fused p2+scan1: per node, scan all PB=256 hist rows (8 chunks x 32
// register-pipelined independent loads), write 8-byte chunkoff, then block-scan
// per-node totals -> partial rowptr + per-block sum.
__global__ __launch_bounds__(256) void k_p2s1(unsigned char* __restrict__ hist,
                                              unsigned char* __restrict__ chunkoff,
                                              int* __restrict__ rowptr,
                                              int* __restrict__ bsum) {
    __shared__ int sh[256];
    int t = threadIdx.x;
    int n = blockIdx.x * 256 + t;
    int v = 0;
    if (n < NN) {
        unsigned int runs[NCH];
#pragma unroll
        for (int c = 0; c < NCH; ++c) {
            size_t base = (size_t)(c * BPC) * NN + n;
            unsigned int vv[BPC];
#pragma unroll
            for (int b = 0; b < BPC; ++b) vv[b] = hist[base + (size_t)b * NN];
            unsigned int run = 0;
#pragma unroll
            for (int b = 0; b < BPC; ++b) { unsigned int x = vv[b]; vv[b] = run; run += x; }
#pragma unroll
            for (int b = 0; b < BPC; ++b) hist[base + (size_t)b * NN] = (unsigned char)vv[b];
            runs[c] = run;
        }
        unsigned int off = 0;
        unsigned int w0 = 0, w1 = 0;
#pragma unroll
        for (int c = 0; c < NCH; ++c) {
            if (c < 4) w0 |= (off & 0xffu) << (8 * c);
            else       w1 |= (off & 0xffu) << (8 * (c - 4));
            off += runs[c];
        }
        *(unsigned int*)&chunkoff[(size_t)n * 8]     = w0;
        *(unsigned int*)&chunkoff[(size_t)n * 8 + 4] = w1;
        v = (int)off;
    }
    sh[t] = v; __syncthreads();
    for (int off = 1; off < 256; off <<= 1) {
        int x = (t >= off) ? sh[t - off] : 0;
        __syncthreads();
        sh[t] += x;
        __syncthreads();
    }
    if (n < NN) rowptr[n] = sh[t] - v;
    if (t == 255) bsum[blockIdx.x] = sh[255];
}

// CSR fill + folded scan2/scan3: every block scans bsum (196 ints) in LDS,
// uses the exclusive offsets for pos, and writes the finalized rowptrF.
__global__ __launch_bounds__(256) void k_fill(const int* __restrict__ ei,
                                              const unsigned char* __restrict__ rank8,
                                              const unsigned char* __restrict__ hist,
                                              const unsigned char* __restrict__ chunkoff,
                                              const int* __restrict__ rowptr,
                                              const int* __restrict__ bsum,
                                              unsigned short* __restrict__ col,
                                              int* __restrict__ rowptrF) {
    __shared__ int sb[256];
    int t = threadIdx.x;
    int v = (t < NB) ? bsum[t] : 0;
    sb[t] = v; __syncthreads();
    for (int off = 1; off < 256; off <<= 1) {
        int x = (t >= off) ? sb[t - off] : 0;
        __syncthreads();
        sb[t] += x;
        __syncthreads();
    }
    sb[t] -= v;              // exclusive scan
    __syncthreads();
    int i = blockIdx.x * 256 + t;
    if (i < EP) {
        int b = i / CH;      // hist block-row (const divide -> magic mul)
        int c = b / BPC;     // chunk
        int s, d; edge_sd(ei, i, s, d);
        int pos = rowptr[d] + sb[d >> 8] + (int)chunkoff[(size_t)d * 8 + c]
                + (int)hist[(size_t)b * NN + d] + (int)rank8[i];
        col[pos] = (unsigned short)s;
    }
    if (i < NN) rowptrF[i] = rowptr[i] + sb[i >> 8];
    if (i == 0) rowptrF[NN] = EP;
}

// edge-order alpha output (coalesced NT write; score arrays L2-resident)
__global__ void k_alpha_out(const int* __restrict__ ei, const float* __restrict__ as_,
                            const float* __restrict__ ad_, const float* __restrict__ inv,
                            float* __restrict__ out_alpha) {
    int i = blockIdx.x * blockDim.x + threadIdx.x;
    if (i >= EP) return;
    int s, d; edge_sd(ei, i, s, d);
    float v = as_[s] + ad_[d];
    v = v > 0.f ? v : NEG_SLOPE * v;
    __builtin_nontemporal_store(__expf(v) * inv[d], &out_alpha[i]);
}

// ---------------- dense GEMM + fused alpha scores ----------------
struct alignas(8) bh4 { __hip_bfloat16 a, b, c, d; };

__device__ inline void fma4(float4& acc, float x, const float4& w) {
    acc.x = fmaf(x, w.x, acc.x);
    acc.y = fmaf(x, w.y, acc.y);
    acc.z = fmaf(x, w.z, acc.z);
    acc.w = fmaf(x, w.w, acc.w);
}

template <int FIN, int FOUT, int NPB>
__global__ __launch_bounds__(256) void k_gemm_t(const float* __restrict__ in,
                                                const float* __restrict__ W,
                                                const float* __restrict__ avs,
                                                const float* __restrict__ avd,
                                                __hip_bfloat16* __restrict__ H,
                                                float* __restrict__ as_,
                                                float* __restrict__ ad_, int n) {
    constexpr int TF = FOUT / 4;
    constexpr int XS = FIN + 4;
    constexpr int WS = FOUT + 4;
    __shared__ float sX[NPB * XS];
    __shared__ float sWt[FIN * WS];
    int tid = threadIdx.x;
    for (int idx = tid; idx < FIN * FOUT; idx += 256) {
        int f = idx % FOUT, k = idx / FOUT;
        sWt[k * WS + f] = W[f * FIN + k];
    }
    int nb = blockIdx.x * NPB;
    for (int idx = tid; idx < NPB * (FIN / 4); idx += 256) {
        int node = idx / (FIN / 4), kq = idx % (FIN / 4);
        int g = nb + node;
        float4 v = make_float4(0.f, 0.f, 0.f, 0.f);
        if (g < n) v = *(const float4*)&in[(size_t)g * FIN + kq * 4];
        *(float4*)&sX[node * XS + kq * 4] = v;
    }
    __syncthreads();

    int fq = tid % TF, ng = tid / TF;
    int n0 = ng * 4;
    float4 acc0 = make_float4(0.f, 0.f, 0.f, 0.f);
    float4 acc1 = acc0, acc2 = acc0, acc3 = acc0;
    for (int k = 0; k < FIN; k += 4) {
        float4 w0 = *(const float4*)&sWt[(k + 0) * WS + fq * 4];
        float4 w1 = *(const float4*)&sWt[(k + 1) * WS + fq * 4];
        float4 w2 = *(const float4*)&sWt[(k + 2) * WS + fq * 4];
        float4 w3 = *(const float4*)&sWt[(k + 3) * WS + fq * 4];
        float4 x0 = *(const float4*)&sX[(n0 + 0) * XS + k];
        float4 x1 = *(const float4*)&sX[(n0 + 1) * XS + k];
        float4 x2 = *(const float4*)&sX[(n0 + 2) * XS + k];
        float4 x3 = *(const float4*)&sX[(n0 + 3) * XS + k];
        fma4(acc0, x0.x, w0); fma4(acc0, x0.y, w1); fma4(acc0, x0.z, w2); fma4(acc0, x0.w, w3);
        fma4(acc1, x1.x, w0); fma4(acc1, x1.y, w1); fma4(acc1, x1.z, w2); fma4(acc1, x1.w, w3);
        fma4(acc2, x2.x, w0); fma4(acc2, x2.y, w1); fma4(acc2, x2.z, w2); fma4(acc2, x2.w, w3);
        fma4(acc3, x3.x, w0); fma4(acc3, x3.y, w1); fma4(acc3, x3.z, w2); fma4(acc3, x3.w, w3);
    }
    float4 accs[4] = {acc0, acc1, acc2, acc3};
    float4 vs4 = *(const float4*)&avs[fq * 4];
    float4 vd4 = *(const float4*)&avd[fq * 4];
#pragma unroll
    for (int j = 0; j < 4; ++j) {
        int g = nb + n0 + j;
        float ps = accs[j].x * vs4.x + accs[j].y * vs4.y + accs[j].z * vs4.z + accs[j].w * vs4.w;
        float pd = accs[j].x * vd4.x + accs[j].y * vd4.y + accs[j].z * vd4.z + accs[j].w * vd4.w;
#pragma unroll
        for (int off = TF / 2; off; off >>= 1) {
            ps += __shfl_down(ps, off, TF);
            pd += __shfl_down(pd, off, TF);
        }
        if (g < n) {
            if (fq == 0) { as_[g] = ps; ad_[g] = pd; }
            bh4 o;
            o.a = __float2bfloat16(accs[j].x);
            o.b = __float2bfloat16(accs[j].y);
            o.c = __float2bfloat16(accs[j].z);
            o.d = __float2bfloat16(accs[j].w);
            *(bh4*)&H[(size_t)g * FOUT + fq * 4] = o;
        }
    }
}

// ---------------- per-node softmax + aggregate: GROUP-per-node ----------------
// One L-lane group per node; lane gl owns features 4*gl..4*gl+3. Per 8-edge
// batch each lane issues 8 independent row gathers -> 8-deep memory pipeline
// regardless of node degree. No LDS, VGPR ~55, full occupancy.
template <int FOUT, bool RELU, bool WRITE_INV>
__global__ __launch_bounds__(256) void k_attn_grp(
    const int* __restrict__ rowptr, const unsigned short* __restrict__ col,
    const float* __restrict__ as_, const float* __restrict__ ad_,
    const __hip_bfloat16* __restrict__ H, const float* __restrict__ bias,
    float* __restrict__ outp, float* __restrict__ inv_out) {
    constexpr int L = (FOUT == 64) ? 16 : 8;
    constexpr int GPW = 64 / L;
    int tid = blockIdx.x * 256 + threadIdx.x;
    int wid = tid >> 6;
    int lane = threadIdx.x & 63;
    int grp = lane / L;
    int gl  = lane & (L - 1);
    int node = wid * GPW + grp;
    if (node >= NN) return;

    int start = rowptr[node], end = rowptr[node + 1];
    float adv = ad_[node];
    const uint2* __restrict__ H4 = (const uint2*)H;
    int base = lane & ~(L - 1);

    float sloc = 0.f;
    float4 acc = make_float4(0.f, 0.f, 0.f, 0.f);
    for (int c = start; c < end; c += 8) {
        int e = c + gl;
        float p = 0.f;
        int sc = 0;
        if (gl < 8 && e < end) {
            sc = (int)col[e];
            float v = as_[sc] + adv;
            v = v > 0.f ? v : NEG_SLOPE * v;
            p = __expf(v);
        }
        sloc += p;
        int cnt = end - c; if (cnt > 8) cnt = 8;
        float pp[8]; int ss[8]; uint2 hh[8];
#pragma unroll
        for (int k = 0; k < 8; ++k) {
            pp[k] = __shfl(p, base + k);
            ss[k] = __shfl(sc, base + k);
        }
#pragma unroll
        for (int k = 0; k < 8; ++k) {
            hh[k] = make_uint2(0u, 0u);
            if (k < cnt) hh[k] = H4[(size_t)ss[k] * L + gl];
        }
#pragma unroll
        for (int k = 0; k < 8; ++k) {
            acc.x = fmaf(pp[k], bflo(hh[k].x), acc.x);
            acc.y = fmaf(pp[k], bfhi(hh[k].x), acc.y);
            acc.z = fmaf(pp[k], bflo(hh[k].y), acc.z);
            acc.w = fmaf(pp[k], bfhi(hh[k].y), acc.w);
        }
    }
#pragma unroll
    for (int off = L / 2; off; off >>= 1) sloc += __shfl_xor(sloc, off);
    float inv = 1.f / (sloc + GAT_EPS);
    if (WRITE_INV && gl == 0) inv_out[node] = inv;

    float4 bb = *(const float4*)&bias[gl * 4];
    float o0 = bb.x + acc.x * inv;
    float o1 = bb.y + acc.y * inv;
    float o2 = bb.z + acc.z * inv;
    float o3 = bb.w + acc.w * inv;
    if (RELU) {
        o0 = fmaxf(o0, 0.f); o1 = fmaxf(o1, 0.f);
        o2 = fmaxf(o2, 0.f); o3 = fmaxf(o3, 0.f);
    }
    *(float4*)&outp[(size_t)node * FOUT + gl * 4] = make_float4(o0, o1, o2, o3);
}

extern "C" void kernel_launch(void* const* d_in, const int* in_sizes, int n_in,
                              void* d_out, int out_size, void* d_ws, size_t ws_size,
                              hipStream_t stream) {
    const float* x  = (const float*)d_in[0];
    const int*   ei = (const int*)d_in[1];
    const float* W1 = (const float*)d_in[2];
    const float* as1 = (const float*)d_in[3];
    const float* ad1 = (const float*)d_in[4];
    const float* b1 = (const float*)d_in[5];
    const float* W2 = (const float*)d_in[6];
    const float* as2 = (const float*)d_in[7];
    const float* ad2 = (const float*)d_in[8];
    const float* b2 = (const float*)d_in[9];
    const float* W3 = (const float*)d_in[10];
    const float* as3 = (const float*)d_in[11];
    const float* ad3 = (const float*)d_in[12];
    const float* b3 = (const float*)d_in[13];

    float* out = (float*)d_out;
    float* out_edges = out;                 // [2, EP]
    float* out_alpha = out + 2 * EP;        // [EP]
    float* out_final = out + 3 * EP;        // [N, 32]

    char* w = (char*)d_ws;
    size_t o = 0;
    auto alloc = [&](size_t bytes) { void* p = w + o; o = (o + bytes + 15) & ~15ull; return p; };
    float* as_ = (float*)alloc((size_t)NN * 4);
    float* ad_ = (float*)alloc((size_t)NN * 4);
    float* inv = (float*)alloc((size_t)NN * 4);
    __hip_bfloat16* H = (__hip_bfloat16*)alloc((size_t)NN * 64 * 2); // 6.4MB
    int* rowptr  = (int*)alloc((size_t)(NN + 1) * 4);
    int* rowptrF = (int*)alloc((size_t)(NN + 1) * 4);
    unsigned char* rank8 = (unsigned char*)alloc((size_t)EP);        // 0.85MB
    unsigned short* col  = (unsigned short*)alloc((size_t)EP * 2);   // 1.7MB
    unsigned char* chunkoff = (unsigned char*)alloc((size_t)NN * 8); // 400KB
    int* bsum = (int*)alloc(1024);
    float* agg = (float*)alloc((size_t)NN * 64 * 4);                 // 12.8MB
    unsigned char* hist = (unsigned char*)alloc((size_t)PB * NN);    // 12.8MB
    (void)ws_size; // total ~36MB << 256MiB workspace (verified by poison size)

    // --- CSR build: 3 launches ---
    k_p1_hist<<<PB, PT, 0, stream>>>(ei, out_edges, hist, rank8);
    k_p2s1<<<NB, 256, 0, stream>>>(hist, chunkoff, rowptr, bsum);
    k_fill<<<(EP + 255) / 256, 256, 0, stream>>>(ei, rank8, hist, chunkoff, rowptr, bsum,
                                                 col, rowptrF);

    const int nblk64 = (NN + 15) / 16;   // 16 nodes/block
    const int nblk32 = (NN + 31) / 32;   // 32 nodes/block

    // layer 1: 128 -> 64, ReLU fused; stores inv[] for the alpha pass
    k_gemm_t<128, 64, 64><<<(NN + 63) / 64, 256, 0, stream>>>(x, W1, as1, ad1, H, as_, ad_, NN);
    k_attn_grp<64, true, true><<<nblk64, 256, 0, stream>>>(rowptrF, col, as_, ad_, H, b1,
                                                           agg, inv);
    k_alpha_out<<<(EP + 255) / 256, 256, 0, stream>>>(ei, as_, ad_, inv, out_alpha);

    // layer 2: 64 -> 64, ReLU fused
    k_gemm_t<64, 64, 64><<<(NN + 63) / 64, 256, 0, stream>>>(agg, W2, as2, ad2, H, as_, ad_, NN);
    k_attn_grp<64, true, false><<<nblk64, 256, 0, stream>>>(rowptrF, col, as_, ad_, H, b2,
                                                            agg, nullptr);

    // layer 3: 64 -> 32, straight into d_out chunk 2
    k_gemm_t<64, 32, 128><<<(NN + 127) / 128, 256, 0, stream>>>(agg, W3, as3, ad3, H, as_, ad_,
                                                                NN);
    k_attn_grp<32, false, false><<<nblk32, 256, 0, stream>>>(rowptrF, col, as_, ad_, H, b3,
                                                             out_final, nullptr);
}